// Round 1
// baseline (219.000 us; speedup 1.0000x reference)
//
#include <hip/hip_runtime.h>
#include <math.h>

#define NN   2048
#define BB   16
#define FDIM 128
#define DD   32
#define NH   4
#define HD8  8

// ws layout (float offsets)
#define WS_X0   0
#define WS_QT   65536
#define WS_KT   131072
#define WS_VT   196608
#define WS_AO   262144
#define WS_SOUT 327680
#define WS_GI   360448

__device__ __forceinline__ float sigmoidf_(float x) { return 1.0f / (1.0f + __expf(-x)); }
__device__ __forceinline__ float dot4_(float4 a, float4 b) {
    return a.x*b.x + a.y*b.y + a.z*b.z + a.w*b.w;
}

// ---------------------------------------------------------------------------
// K1: blocks 0..255: x0 = nf@Wemb^T+b ; qkv = x0@Wqkv^T+b  (head-major q/k/v)
//     block 256:     messages -> gi = msg@Wih^T + bih   (for the GRU scan)
// ---------------------------------------------------------------------------
__global__ __launch_bounds__(256) void k1_embed_qkv(
    const float* __restrict__ nf, const float* __restrict__ Wemb, const float* __restrict__ bemb,
    const float* __restrict__ Wqkv, const float* __restrict__ bqkv,
    const float* __restrict__ mem, const int* __restrict__ src, const int* __restrict__ dst,
    const float* __restrict__ ef,
    const float* __restrict__ Wm1, const float* __restrict__ bm1,
    const float* __restrict__ Wm2, const float* __restrict__ bm2,
    const float* __restrict__ Wih, const float* __restrict__ bih,
    float* __restrict__ ws)
{
    // node path LDS (odd strides -> conflict-free reads)
    __shared__ float We_s[32 * 129];
    __shared__ float nf_s[8 * 129];
    __shared__ float x0_s[8 * 33];
    __shared__ float Wq_s[96 * 33];
    // message path LDS
    __shared__ float Wm1_s[32 * 67];
    __shared__ float Wm2_s[32 * 33];
    __shared__ float Wih_s[96 * 33];
    __shared__ float min_s[16 * 67];
    __shared__ float mr_s[16 * 33];
    __shared__ float msg_s[16 * 33];

    const int t = threadIdx.x;

    if (blockIdx.x == 256) {
        // ---- message path ----
        for (int idx = t; idx < 32 * 67; idx += 256) Wm1_s[idx] = Wm1[idx]; // stride 67 natural
        for (int idx = t; idx < 1024; idx += 256) { int o = idx >> 5, i = idx & 31; Wm2_s[o * 33 + i] = Wm2[idx]; }
        for (int idx = t; idx < 3072; idx += 256) { int o = idx >> 5, i = idx & 31; Wih_s[o * 33 + i] = Wih[idx]; }
        for (int idx = t; idx < 16 * 67; idx += 256) {
            int e = idx / 67, i = idx - e * 67;
            float v;
            if (i < 32)      v = mem[src[e] * 32 + i];
            else if (i < 64) v = mem[dst[e] * 32 + (i - 32)];
            else             v = ef[e * 3 + (i - 64)];
            min_s[idx] = v;
        }
        __syncthreads();
        {
            int o = t & 31, e0 = t >> 5;
            for (int p = 0; p < 2; ++p) {
                int e = e0 + p * 8;
                float acc = bm1[o];
                for (int i = 0; i < 67; ++i) acc += Wm1_s[o * 67 + i] * min_s[e * 67 + i];
                mr_s[e * 33 + o] = fmaxf(acc, 0.f);
            }
        }
        __syncthreads();
        {
            int o = t & 31, e0 = t >> 5;
            for (int p = 0; p < 2; ++p) {
                int e = e0 + p * 8;
                float acc = bm2[o];
                #pragma unroll 8
                for (int i = 0; i < 32; ++i) acc += Wm2_s[o * 33 + i] * mr_s[e * 33 + i];
                msg_s[e * 33 + o] = acc;
            }
        }
        __syncthreads();
        {
            float* gi_g = ws + WS_GI;
            for (int idx = t; idx < 1536; idx += 256) {
                int e = idx / 96, o = idx - e * 96;
                float acc = bih[o];
                #pragma unroll 8
                for (int i = 0; i < 32; ++i) acc += Wih_s[o * 33 + i] * msg_s[e * 33 + i];
                gi_g[idx] = acc;  // [e][96]
            }
        }
        return;
    }

    // ---- node path: 8 nodes per block ----
    const int j = t >> 5, o = t & 31;
    const int n = blockIdx.x * 8 + j;

    for (int idx = t; idx < 4096; idx += 256) { int r = idx >> 7, c = idx & 127; We_s[r * 129 + c] = Wemb[idx]; }
    for (int idx = t; idx < 3072; idx += 256) { int r = idx >> 5, c = idx & 31;  Wq_s[r * 33 + c] = Wqkv[idx]; }
    for (int idx = t; idx < 1024; idx += 256) {
        int r = idx >> 7, c = idx & 127;
        nf_s[r * 129 + c] = nf[(blockIdx.x * 8 + r) * 128 + c];
    }
    __syncthreads();

    float acc = bemb[o];
    #pragma unroll 8
    for (int i = 0; i < 128; ++i) acc += We_s[o * 129 + i] * nf_s[j * 129 + i];
    x0_s[j * 33 + o] = acc;
    ws[WS_X0 + n * 32 + o] = acc;
    __syncthreads();

    #pragma unroll
    for (int c = 0; c < 3; ++c) {
        int oo = c * 32 + o;
        float a2 = bqkv[oo];
        #pragma unroll 8
        for (int i = 0; i < 32; ++i) a2 += Wq_s[oo * 33 + i] * x0_s[j * 33 + i];
        int h = o >> 3, d = o & 7;
        float* base = ws + (c == 0 ? WS_QT : (c == 1 ? WS_KT : WS_VT));
        base[h * 16384 + n * 8 + d] = a2;  // [h][n][d]
    }
}

// ---------------------------------------------------------------------------
// K2: attention. block = (head, 32 queries). K/V staged in LDS in 2 halves.
// wave: lane = qi*8 + kg  (8 queries x 8 key-groups). Max-free online softmax.
// ---------------------------------------------------------------------------
__global__ __launch_bounds__(256) void k2_attn(float* __restrict__ ws)
{
    __shared__ __align__(16) float Ks[1024 * 8];
    __shared__ __align__(16) float Vs[1024 * 8];

    const int t = threadIdx.x;
    const int h  = blockIdx.x >> 6;
    const int qb = blockIdx.x & 63;
    const int l = t & 63, w = t >> 6;
    const int qi = w * 8 + (l >> 3);
    const int kg = l & 7;
    const int nq = qb * 32 + qi;

    const float* qg = ws + WS_QT + h * 16384;
    const float* kgl = ws + WS_KT + h * 16384;
    const float* vgl = ws + WS_VT + h * 16384;

    const float4 qa  = *(const float4*)(qg + nq * 8);
    const float4 qb4 = *(const float4*)(qg + nq * 8 + 4);

    float4 oa = make_float4(0.f, 0.f, 0.f, 0.f);
    float4 ob = make_float4(0.f, 0.f, 0.f, 0.f);
    float ssum = 0.f;
    const float scale = 0.35355339059327373f;  // 1/sqrt(8)

    for (int half = 0; half < 2; ++half) {
        const float4* ksrc = (const float4*)(kgl + half * 8192);
        const float4* vsrc = (const float4*)(vgl + half * 8192);
        float4* kd = (float4*)Ks;
        float4* vd = (float4*)Vs;
        for (int idx = t; idx < 2048; idx += 256) { kd[idx] = ksrc[idx]; vd[idx] = vsrc[idx]; }
        __syncthreads();

        #pragma unroll 4
        for (int key = kg; key < 1024; key += 8) {
            const float4 ka = *(const float4*)&Ks[key * 8];
            const float4 kb = *(const float4*)&Ks[key * 8 + 4];
            float s = dot4_(qa, ka) + dot4_(qb4, kb);
            float p = __expf(s * scale);
            ssum += p;
            const float4 va = *(const float4*)&Vs[key * 8];
            const float4 vb = *(const float4*)&Vs[key * 8 + 4];
            oa.x += p * va.x; oa.y += p * va.y; oa.z += p * va.z; oa.w += p * va.w;
            ob.x += p * vb.x; ob.y += p * vb.y; ob.z += p * vb.z; ob.w += p * vb.w;
        }
        __syncthreads();
    }

    // combine over the 8 key-group lanes (xor masks 1,2,4 stay inside group)
    #pragma unroll
    for (int m = 1; m <= 4; m <<= 1) {
        ssum += __shfl_xor(ssum, m);
        oa.x += __shfl_xor(oa.x, m); oa.y += __shfl_xor(oa.y, m);
        oa.z += __shfl_xor(oa.z, m); oa.w += __shfl_xor(oa.w, m);
        ob.x += __shfl_xor(ob.x, m); ob.y += __shfl_xor(ob.y, m);
        ob.z += __shfl_xor(ob.z, m); ob.w += __shfl_xor(ob.w, m);
    }
    if (kg == 0) {
        float inv = 1.0f / ssum;
        float* aop = ws + WS_AO + nq * 32 + h * 8;
        *(float4*)aop       = make_float4(oa.x * inv, oa.y * inv, oa.z * inv, oa.w * inv);
        *(float4*)(aop + 4) = make_float4(ob.x * inv, ob.y * inv, ob.z * inv, ob.w * inv);
    }
}

// ---------------------------------------------------------------------------
// K3: per-node epilogue: Wo -> +x0 -> LN1 -> FFN(gelu) -> LN2 -> SCN LN relu.
// Also copies memory -> d_out[16..] (float4).
// ---------------------------------------------------------------------------
__global__ __launch_bounds__(256) void k3_post(
    const float* __restrict__ mem,
    const float* __restrict__ Wo, const float* __restrict__ bo,
    const float* __restrict__ g1, const float* __restrict__ be1,
    const float* __restrict__ Wf1, const float* __restrict__ bf1,
    const float* __restrict__ Wf2, const float* __restrict__ bf2,
    const float* __restrict__ g2, const float* __restrict__ be2,
    const float* __restrict__ Wscn, const float* __restrict__ bscn,
    const float* __restrict__ gscn, const float* __restrict__ bescn,
    float* __restrict__ ws, float* __restrict__ out)
{
    __shared__ float Wo_s[32 * 33];
    __shared__ float Wf1_s[64 * 33];
    __shared__ float Wf2_s[32 * 65];
    __shared__ float Ws_s[16 * 33];
    __shared__ float arow[8 * 33];
    __shared__ float x1s[8 * 33];
    __shared__ float fs[8 * 65];

    const int t = threadIdx.x, bx = blockIdx.x;

    { // bulk copy memory -> out (rows later overwritten by K4 for touched nodes)
        int g = bx * 256 + t;
        if (g < 16384) ((float4*)(out + 16))[g] = ((const float4*)mem)[g];
    }

    for (int idx = t; idx < 1024; idx += 256) { int r = idx >> 5, c = idx & 31; Wo_s[r * 33 + c] = Wo[idx]; }
    for (int idx = t; idx < 2048; idx += 256) { int r = idx >> 5, c = idx & 31; Wf1_s[r * 33 + c] = Wf1[idx]; }
    for (int idx = t; idx < 2048; idx += 256) { int r = idx >> 6, c = idx & 63; Wf2_s[r * 65 + c] = Wf2[idx]; }
    for (int idx = t; idx < 512;  idx += 256) { int r = idx >> 5, c = idx & 31; Ws_s[r * 33 + c] = Wscn[idx]; }

    const int j = t >> 5, o = t & 31;
    const int n = bx * 8 + j;
    arow[j * 33 + o] = ws[WS_AO + n * 32 + o];
    const float x0v = ws[WS_X0 + n * 32 + o];
    __syncthreads();

    // Wo + residual
    float a = bo[o];
    #pragma unroll 8
    for (int i = 0; i < 32; ++i) a += Wo_s[o * 33 + i] * arow[j * 33 + i];
    float t1 = x0v + a;

    // LN1 (32-lane groups)
    float mu = t1;
    #pragma unroll
    for (int m = 16; m >= 1; m >>= 1) mu += __shfl_xor(mu, m, 32);
    mu *= (1.f / 32.f);
    float dv = t1 - mu;
    float var = dv * dv;
    #pragma unroll
    for (int m = 16; m >= 1; m >>= 1) var += __shfl_xor(var, m, 32);
    var *= (1.f / 32.f);
    float x1 = dv * rsqrtf(var + 1e-5f) * g1[o] + be1[o];
    x1s[j * 33 + o] = x1;
    __syncthreads();

    // FFN1 + exact gelu
    #pragma unroll
    for (int c = 0; c < 2; ++c) {
        int oo = c * 32 + o;
        float f = bf1[oo];
        #pragma unroll 8
        for (int i = 0; i < 32; ++i) f += Wf1_s[oo * 33 + i] * x1s[j * 33 + i];
        fs[j * 65 + oo] = 0.5f * f * (1.f + erff(f * 0.70710678118654752f));
    }
    __syncthreads();

    // FFN2 + residual + LN2
    float f2 = bf2[o];
    #pragma unroll 8
    for (int i = 0; i < 64; ++i) f2 += Wf2_s[o * 65 + i] * fs[j * 65 + i];
    float t2 = x1 + f2;
    float mu2 = t2;
    #pragma unroll
    for (int m = 16; m >= 1; m >>= 1) mu2 += __shfl_xor(mu2, m, 32);
    mu2 *= (1.f / 32.f);
    float dv2 = t2 - mu2;
    float var2 = dv2 * dv2;
    #pragma unroll
    for (int m = 16; m >= 1; m >>= 1) var2 += __shfl_xor(var2, m, 32);
    var2 *= (1.f / 32.f);
    float x2 = dv2 * rsqrtf(var2 + 1e-5f) * g2[o] + be2[o];

    x1s[j * 33 + o] = x2;   // safe: prior x1s reads all completed before last barrier
    __syncthreads();

    // SCN: 16 outputs, LN over 16, relu
    if (o < 16) {
        float s = bscn[o];
        #pragma unroll 8
        for (int i = 0; i < 32; ++i) s += Ws_s[o * 33 + i] * x1s[j * 33 + i];
        float m16 = s;
        #pragma unroll
        for (int m = 8; m >= 1; m >>= 1) m16 += __shfl_xor(m16, m, 16);
        m16 *= (1.f / 16.f);
        float d16 = s - m16;
        float v16 = d16 * d16;
        #pragma unroll
        for (int m = 8; m >= 1; m >>= 1) v16 += __shfl_xor(v16, m, 16);
        v16 *= (1.f / 16.f);
        float sv = d16 * rsqrtf(v16 + 1e-5f) * gscn[o] + bescn[o];
        ws[WS_SOUT + n * 16 + o] = fmaxf(sv, 0.f);
    }
}

// ---------------------------------------------------------------------------
// K4: single wave. Edge-head MLP -> logits; sequential GRU scan over 16 edges
// (src & dst GRUs in parallel when distinct). Whh rows held in registers.
// ---------------------------------------------------------------------------
__global__ __launch_bounds__(64) void k4_scan(
    const int* __restrict__ src, const int* __restrict__ dst,
    const float* __restrict__ mem,
    const float* __restrict__ Whh, const float* __restrict__ bhh,
    const float* __restrict__ We1, const float* __restrict__ be1e,
    const float* __restrict__ We2, const float* __restrict__ be2e,
    const float* __restrict__ We3, const float* __restrict__ be3,
    float* __restrict__ ws, float* __restrict__ out)
{
    __shared__ float We1_s[32 * 33];
    __shared__ float We2_s[16 * 33];
    __shared__ float cat_s[16 * 33];
    __shared__ float h1_s[16 * 33];
    __shared__ float h2_s[16 * 17];
    __shared__ float gi_s[16 * 97];
    __shared__ __align__(16) float slots[32 * 36];
    __shared__ int nid_s[32], fid_s[32], last_s[32];

    const int l = threadIdx.x;

    for (int idx = l; idx < 1024; idx += 64) { int r = idx >> 5, c = idx & 31; We1_s[r * 33 + c] = We1[idx]; }
    for (int idx = l; idx < 512;  idx += 64) { int r = idx >> 5, c = idx & 31; We2_s[r * 33 + c] = We2[idx]; }
    {
        const float* gi_g = ws + WS_GI;
        for (int idx = l; idx < 1536; idx += 64) { int e = idx / 96, o = idx - e * 96; gi_s[e * 97 + o] = gi_g[idx]; }
    }
    {
        const float* sout = ws + WS_SOUT;
        for (int idx = l; idx < 512; idx += 64) {
            int e = idx >> 5, i = idx & 31;
            cat_s[e * 33 + i] = (i < 16) ? sout[src[e] * 16 + i] : sout[dst[e] * 16 + (i - 16)];
        }
    }
    if (l < 32) nid_s[l] = (l & 1) ? dst[l >> 1] : src[l >> 1];
    __syncthreads();

    if (l < 32) {
        int me = nid_s[l], f = l;
        for (int j2 = 0; j2 < l; ++j2) if (nid_s[j2] == me) { f = j2; break; }
        fid_s[l] = f;
        int isl = 1;
        for (int j2 = l + 1; j2 < 32; ++j2) if (nid_s[j2] == me) { isl = 0; break; }
        last_s[l] = isl;
    }
    __syncthreads();

    // load memory rows into slots (first occurrences only)
    for (int idx = l; idx < 1024; idx += 64) {
        int j2 = idx >> 5, o = idx & 31;
        if (fid_s[j2] == j2) slots[j2 * 36 + o] = mem[nid_s[j2] * 32 + o];
    }

    // ---- edge head ----
    {
        int o = l & 31, eh = l >> 5;
        for (int p = 0; p < 8; ++p) {
            int e = p * 2 + eh;
            float acc = be1e[o];
            #pragma unroll 8
            for (int i = 0; i < 32; ++i) acc += We1_s[o * 33 + i] * cat_s[e * 33 + i];
            h1_s[e * 33 + o] = fmaxf(acc, 0.f);
        }
    }
    __syncthreads();
    {
        int o = l & 15, eh = l >> 4;
        for (int p = 0; p < 4; ++p) {
            int e = p * 4 + eh;
            float acc = be2e[o];
            #pragma unroll 8
            for (int i = 0; i < 32; ++i) acc += We2_s[o * 33 + i] * h1_s[e * 33 + i];
            h2_s[e * 17 + o] = fmaxf(acc, 0.f);
        }
    }
    __syncthreads();
    if (l < 16) {
        float acc = be3[0];
        #pragma unroll
        for (int i = 0; i < 16; ++i) acc += We3[i] * h2_s[l * 17 + i];
        out[l] = acc;
    }
    __syncthreads();

    // ---- GRU scan ----
    const int r2 = (l < 32) ? l + 64 : l - 32;
    const int r3 = l + 32;
    float4 w1[8], w2[8], w3[8];
    #pragma unroll
    for (int c = 0; c < 8; ++c) {
        w1[c] = ((const float4*)Whh)[l * 8 + c];
        w2[c] = ((const float4*)Whh)[r2 * 8 + c];
        w3[c] = ((const float4*)Whh)[r3 * 8 + c];
    }
    const float b1 = bhh[l], b2 = bhh[r2], b3 = bhh[r3];
    const bool lowhalf = (l < 32);
    const int o = l & 31;

    for (int e = 0; e < 16; ++e) {
        const int js = 2 * e, jd = 2 * e + 1;
        const int ss = fid_s[js], sd = fid_s[jd];
        const bool same = (nid_s[js] == nid_s[jd]);
        const int npass = same ? 2 : 1;
        for (int pass = 0; pass < npass; ++pass) {
            const bool do_src = (!same) || (pass == 0);
            const bool do_dst = (!same) || (pass == 1);
            float acc1 = b1, acc2 = b2, acc3 = b3;
            #pragma unroll
            for (int c = 0; c < 8; ++c) {
                const float4 hs4 = *(const float4*)&slots[ss * 36 + 4 * c];
                const float4 hd4 = *(const float4*)&slots[sd * 36 + 4 * c];
                acc1 += dot4_(w1[c], hs4);
                const float4 hm = lowhalf ? hs4 : hd4;
                acc2 += dot4_(w2[c], hm);
                acc3 += dot4_(w3[c], hd4);
            }
            const float shv = __shfl_xor(lowhalf ? acc3 : acc1, 32);
            const float hr = lowhalf ? acc1 : acc2;
            const float hz = shv;
            const float hn = lowhalf ? acc2 : acc3;
            const float ir  = gi_s[e * 97 + o];
            const float iz  = gi_s[e * 97 + 32 + o];
            const float inn = gi_s[e * 97 + 64 + o];
            const float r = sigmoidf_(ir + hr);
            const float z = sigmoidf_(iz + hz);
            const float nn = tanhf(inn + r * hn);
            const int slot = lowhalf ? ss : sd;
            const float hold = slots[slot * 36 + o];
            const float hnew = (1.f - z) * nn + z * hold;
            const bool wr = lowhalf ? do_src : do_dst;
            if (wr) slots[slot * 36 + o] = hnew;
            __syncthreads();
        }
    }

    // write back last occurrence of each node
    for (int idx = l; idx < 1024; idx += 64) {
        int j2 = idx >> 5, oo = idx & 31;
        if (last_s[j2]) out[16 + nid_s[j2] * 32 + oo] = slots[fid_s[j2] * 36 + oo];
    }
}

// ---------------------------------------------------------------------------
extern "C" void kernel_launch(void* const* d_in, const int* in_sizes, int n_in,
                              void* d_out, int out_size, void* d_ws, size_t ws_size,
                              hipStream_t stream)
{
    (void)in_sizes; (void)n_in; (void)out_size; (void)ws_size;
    const int*   src   = (const int*)d_in[0];
    const int*   dst   = (const int*)d_in[1];
    const float* ef    = (const float*)d_in[2];
    const float* nf    = (const float*)d_in[4];
    const float* mem   = (const float*)d_in[6];
    const float* Wemb  = (const float*)d_in[7];
    const float* bemb  = (const float*)d_in[8];
    const float* Wqkv  = (const float*)d_in[9];
    const float* bqkv  = (const float*)d_in[10];
    const float* Wo    = (const float*)d_in[11];
    const float* bo    = (const float*)d_in[12];
    const float* g1    = (const float*)d_in[13];
    const float* be1   = (const float*)d_in[14];
    const float* g2    = (const float*)d_in[15];
    const float* be2   = (const float*)d_in[16];
    const float* Wf1   = (const float*)d_in[17];
    const float* bf1   = (const float*)d_in[18];
    const float* Wf2   = (const float*)d_in[19];
    const float* bf2   = (const float*)d_in[20];
    const float* Wscn  = (const float*)d_in[21];
    const float* bscn  = (const float*)d_in[22];
    const float* gscn  = (const float*)d_in[23];
    const float* bescn = (const float*)d_in[24];
    const float* We1   = (const float*)d_in[25];
    const float* be1e  = (const float*)d_in[26];
    const float* We2   = (const float*)d_in[27];
    const float* be2e  = (const float*)d_in[28];
    const float* We3   = (const float*)d_in[29];
    const float* be3   = (const float*)d_in[30];
    const float* Wih   = (const float*)d_in[31];
    const float* bih   = (const float*)d_in[32];
    const float* Whh   = (const float*)d_in[33];
    const float* bhh   = (const float*)d_in[34];
    const float* Wm1   = (const float*)d_in[35];
    const float* bm1   = (const float*)d_in[36];
    const float* Wm2   = (const float*)d_in[37];
    const float* bm2   = (const float*)d_in[38];
    float* out = (float*)d_out;
    float* ws  = (float*)d_ws;

    hipLaunchKernelGGL(k1_embed_qkv, dim3(257), dim3(256), 0, stream,
        nf, Wemb, bemb, Wqkv, bqkv, mem, src, dst, ef, Wm1, bm1, Wm2, bm2, Wih, bih, ws);
    hipLaunchKernelGGL(k2_attn, dim3(256), dim3(256), 0, stream, ws);
    hipLaunchKernelGGL(k3_post, dim3(256), dim3(256), 0, stream,
        mem, Wo, bo, g1, be1, Wf1, bf1, Wf2, bf2, g2, be2, Wscn, bscn, gscn, bescn, ws, out);
    hipLaunchKernelGGL(k4_scan, dim3(1), dim3(64), 0, stream,
        src, dst, mem, Whh, bhh, We1, be1e, We2, be2e, We3, be3, ws, out);
}

// Round 2
// 191.184 us; speedup vs baseline: 1.1455x; 1.1455x over previous
//
#include <hip/hip_runtime.h>
#include <math.h>

#define NN   2048
#define BB   16

// ws layout (float offsets)
#define WS_X0   0
#define WS_QT   65536
#define WS_KT   131072
#define WS_VT   196608
#define WS_PART 262144   // [32 slot][4 h][4 kslice][12]: o[8], ssum, pad
#define WS_SOUT 268288   // [32 slot][16]
#define WS_GI   268800   // [16 edge][96]

__device__ __forceinline__ float sigmoidf_(float x) { return 1.0f / (1.0f + __expf(-x)); }
__device__ __forceinline__ float tanhf_(float x) {
    float ex = __expf(2.0f * x);
    return 1.0f - 2.0f / (ex + 1.0f);
}
__device__ __forceinline__ float dot4_(float4 a, float4 b) {
    return a.x*b.x + a.y*b.y + a.z*b.z + a.w*b.w;
}

// ---------------------------------------------------------------------------
// K1: blocks 0..255: x0 = nf@Wemb^T+b ; qkv = x0@Wqkv^T+b  (head-major q/k/v)
//     block 256:     messages -> gi = msg@Wih^T + bih   (for the GRU scan)
// ---------------------------------------------------------------------------
__global__ __launch_bounds__(256) void k1_embed_qkv(
    const float* __restrict__ nf, const float* __restrict__ Wemb, const float* __restrict__ bemb,
    const float* __restrict__ Wqkv, const float* __restrict__ bqkv,
    const float* __restrict__ mem, const int* __restrict__ src, const int* __restrict__ dst,
    const float* __restrict__ ef,
    const float* __restrict__ Wm1, const float* __restrict__ bm1,
    const float* __restrict__ Wm2, const float* __restrict__ bm2,
    const float* __restrict__ Wih, const float* __restrict__ bih,
    float* __restrict__ ws)
{
    // node path LDS (stride 130: float2-aligned rows, 2-way bank aliasing = free)
    __shared__ float We_s[32 * 130];
    __shared__ float nf_s[8 * 130];
    __shared__ float x0_s[8 * 33];
    __shared__ float Wq_s[96 * 33];
    // message path LDS
    __shared__ float Wm1_s[32 * 67];
    __shared__ float Wm2_s[32 * 33];
    __shared__ float Wih_s[96 * 33];
    __shared__ float min_s[16 * 67];
    __shared__ float mr_s[16 * 33];
    __shared__ float msg_s[16 * 33];

    const int t = threadIdx.x;

    if (blockIdx.x == 256) {
        // ---- message path ----
        for (int idx = t; idx < 32 * 67; idx += 256) Wm1_s[idx] = Wm1[idx];
        for (int idx = t; idx < 1024; idx += 256) { int o = idx >> 5, i = idx & 31; Wm2_s[o * 33 + i] = Wm2[idx]; }
        for (int idx = t; idx < 3072; idx += 256) { int o = idx >> 5, i = idx & 31; Wih_s[o * 33 + i] = Wih[idx]; }
        for (int idx = t; idx < 16 * 67; idx += 256) {
            int e = idx / 67, i = idx - e * 67;
            float v;
            if (i < 32)      v = mem[src[e] * 32 + i];
            else if (i < 64) v = mem[dst[e] * 32 + (i - 32)];
            else             v = ef[e * 3 + (i - 64)];
            min_s[idx] = v;
        }
        __syncthreads();
        {
            int o = t & 31, e0 = t >> 5;
            for (int p = 0; p < 2; ++p) {
                int e = e0 + p * 8;
                float acc = bm1[o];
                for (int i = 0; i < 67; ++i) acc += Wm1_s[o * 67 + i] * min_s[e * 67 + i];
                mr_s[e * 33 + o] = fmaxf(acc, 0.f);
            }
        }
        __syncthreads();
        {
            int o = t & 31, e0 = t >> 5;
            for (int p = 0; p < 2; ++p) {
                int e = e0 + p * 8;
                float acc = bm2[o];
                #pragma unroll 8
                for (int i = 0; i < 32; ++i) acc += Wm2_s[o * 33 + i] * mr_s[e * 33 + i];
                msg_s[e * 33 + o] = acc;
            }
        }
        __syncthreads();
        {
            float* gi_g = ws + WS_GI;
            for (int idx = t; idx < 1536; idx += 256) {
                int e = idx / 96, o = idx - e * 96;
                float acc = bih[o];
                #pragma unroll 8
                for (int i = 0; i < 32; ++i) acc += Wih_s[o * 33 + i] * msg_s[e * 33 + i];
                gi_g[idx] = acc;  // [e][96]
            }
        }
        return;
    }

    // ---- node path: 8 nodes per block ----
    const int j = t >> 5, o = t & 31;
    const int n = blockIdx.x * 8 + j;

    for (int idx = t; idx < 4096; idx += 256) { int r = idx >> 7, c = idx & 127; We_s[r * 130 + c] = Wemb[idx]; }
    for (int idx = t; idx < 3072; idx += 256) { int r = idx >> 5, c = idx & 31;  Wq_s[r * 33 + c] = Wqkv[idx]; }
    for (int idx = t; idx < 1024; idx += 256) {
        int r = idx >> 7, c = idx & 127;
        nf_s[r * 130 + c] = nf[(blockIdx.x * 8 + r) * 128 + c];
    }
    __syncthreads();

    float acc = bemb[o];
    {
        const float2* Wr = (const float2*)&We_s[o * 130];
        const float2* Nr = (const float2*)&nf_s[j * 130];
        float sx = 0.f, sy = 0.f;
        #pragma unroll 16
        for (int i = 0; i < 64; ++i) {
            float2 w = Wr[i], x = Nr[i];
            sx += w.x * x.x; sy += w.y * x.y;
        }
        acc += sx + sy;
    }
    x0_s[j * 33 + o] = acc;
    ws[WS_X0 + n * 32 + o] = acc;
    __syncthreads();

    #pragma unroll
    for (int c = 0; c < 3; ++c) {
        int oo = c * 32 + o;
        float a2 = bqkv[oo];
        #pragma unroll 8
        for (int i = 0; i < 32; ++i) a2 += Wq_s[oo * 33 + i] * x0_s[j * 33 + i];
        int h = o >> 3, d = o & 7;
        float* base = ws + (c == 0 ? WS_QT : (c == 1 ? WS_KT : WS_VT));
        base[h * 16384 + n * 8 + d] = a2;  // [h][n][d]
    }
}

// ---------------------------------------------------------------------------
// K2: attention for the 32 gathered query slots ONLY.
// grid 128 = slot(32) x kslice(4); block 256 = head(4) x 64 lanes.
// Each lane scans 8 keys from global (L2-resident), wave-reduces, writes
// partial (o[8], ssum) per (slot, head, slice). Also folds the mem->out copy.
// ---------------------------------------------------------------------------
__global__ __launch_bounds__(256) void k2_attn(
    const int* __restrict__ src, const int* __restrict__ dst,
    const float* __restrict__ mem,
    float* __restrict__ ws, float* __restrict__ out)
{
    const int t = threadIdx.x, bx = blockIdx.x;

    { // bulk copy memory -> out (rows later overwritten by K4 for touched nodes)
        int g = bx * 256 + t;
        if (g < 16384) ((float4*)(out + 16))[g] = ((const float4*)mem)[g];
    }

    const int s  = bx >> 2;       // slot 0..31
    const int ks = bx & 3;        // key slice 0..3 (512 keys each)
    const int h  = t >> 6;        // head
    const int l  = t & 63;

    const int e = s >> 1;
    const int n = (s & 1) ? dst[e] : src[e];

    const float* qg = ws + WS_QT + h * 16384 + n * 8;
    const float4 qa  = *(const float4*)qg;
    const float4 qb4 = *(const float4*)(qg + 4);
    const float* kbase = ws + WS_KT + h * 16384;
    const float* vbase = ws + WS_VT + h * 16384;

    float4 oa = make_float4(0.f, 0.f, 0.f, 0.f);
    float4 ob = make_float4(0.f, 0.f, 0.f, 0.f);
    float ssum = 0.f;
    const float scale = 0.35355339059327373f;  // 1/sqrt(8)

    #pragma unroll
    for (int i = 0; i < 8; ++i) {
        const int key = ks * 512 + i * 64 + l;
        const float4 ka = *(const float4*)(kbase + key * 8);
        const float4 kb = *(const float4*)(kbase + key * 8 + 4);
        const float sc = (dot4_(qa, ka) + dot4_(qb4, kb)) * scale;
        const float p = __expf(sc);
        ssum += p;
        const float4 va = *(const float4*)(vbase + key * 8);
        const float4 vb = *(const float4*)(vbase + key * 8 + 4);
        oa.x += p * va.x; oa.y += p * va.y; oa.z += p * va.z; oa.w += p * va.w;
        ob.x += p * vb.x; ob.y += p * vb.y; ob.z += p * vb.z; ob.w += p * vb.w;
    }

    #pragma unroll
    for (int m = 1; m <= 32; m <<= 1) {
        ssum += __shfl_xor(ssum, m);
        oa.x += __shfl_xor(oa.x, m); oa.y += __shfl_xor(oa.y, m);
        oa.z += __shfl_xor(oa.z, m); oa.w += __shfl_xor(oa.w, m);
        ob.x += __shfl_xor(ob.x, m); ob.y += __shfl_xor(ob.y, m);
        ob.z += __shfl_xor(ob.z, m); ob.w += __shfl_xor(ob.w, m);
    }
    if (l == 0) {
        float* p = ws + WS_PART + ((s * 4 + h) * 4 + ks) * 12;
        *(float4*)p       = oa;
        *(float4*)(p + 4) = ob;
        p[8] = ssum;
    }
}

// ---------------------------------------------------------------------------
// K3: combine attention partials + per-slot epilogue (32 slots, 4 blocks):
// Wo -> +x0 -> LN1 -> FFN(gelu) -> LN2 -> SCN LN relu -> WS_SOUT[slot].
// ---------------------------------------------------------------------------
__global__ __launch_bounds__(256) void k3_post(
    const int* __restrict__ src, const int* __restrict__ dst,
    const float* __restrict__ Wo, const float* __restrict__ bo,
    const float* __restrict__ g1, const float* __restrict__ be1,
    const float* __restrict__ Wf1, const float* __restrict__ bf1,
    const float* __restrict__ Wf2, const float* __restrict__ bf2,
    const float* __restrict__ g2, const float* __restrict__ be2,
    const float* __restrict__ Wscn, const float* __restrict__ bscn,
    const float* __restrict__ gscn, const float* __restrict__ bescn,
    float* __restrict__ ws)
{
    __shared__ float Wo_s[32 * 33];
    __shared__ float Wf1_s[64 * 33];
    __shared__ float Wf2_s[32 * 65];
    __shared__ float Ws_s[16 * 33];
    __shared__ float arow[8 * 33];
    __shared__ float x1s[8 * 33];
    __shared__ float fs[8 * 65];

    const int t = threadIdx.x, bx = blockIdx.x;

    for (int idx = t; idx < 1024; idx += 256) { int r = idx >> 5, c = idx & 31; Wo_s[r * 33 + c] = Wo[idx]; }
    for (int idx = t; idx < 2048; idx += 256) { int r = idx >> 5, c = idx & 31; Wf1_s[r * 33 + c] = Wf1[idx]; }
    for (int idx = t; idx < 2048; idx += 256) { int r = idx >> 6, c = idx & 63; Wf2_s[r * 65 + c] = Wf2[idx]; }
    for (int idx = t; idx < 512;  idx += 256) { int r = idx >> 5, c = idx & 31; Ws_s[r * 33 + c] = Wscn[idx]; }

    const int j = t >> 5, o = t & 31;
    const int s = bx * 8 + j;
    const int e = s >> 1;
    const int n = (s & 1) ? dst[e] : src[e];

    { // combine 4 key-slice partials for this slot
        const int h = o >> 3, d = o & 7;
        float num = 0.f, den = 0.f;
        #pragma unroll
        for (int ks = 0; ks < 4; ++ks) {
            const float* p = ws + WS_PART + ((s * 4 + h) * 4 + ks) * 12;
            num += p[d];
            den += p[8];
        }
        arow[j * 33 + o] = num / den;
    }
    const float x0v = ws[WS_X0 + n * 32 + o];
    __syncthreads();

    // Wo + residual
    float a = bo[o];
    #pragma unroll 8
    for (int i = 0; i < 32; ++i) a += Wo_s[o * 33 + i] * arow[j * 33 + i];
    float t1 = x0v + a;

    // LN1 (32-lane groups)
    float mu = t1;
    #pragma unroll
    for (int m = 16; m >= 1; m >>= 1) mu += __shfl_xor(mu, m, 32);
    mu *= (1.f / 32.f);
    float dv = t1 - mu;
    float var = dv * dv;
    #pragma unroll
    for (int m = 16; m >= 1; m >>= 1) var += __shfl_xor(var, m, 32);
    var *= (1.f / 32.f);
    float x1 = dv * rsqrtf(var + 1e-5f) * g1[o] + be1[o];
    x1s[j * 33 + o] = x1;
    __syncthreads();

    // FFN1 + exact gelu
    #pragma unroll
    for (int c = 0; c < 2; ++c) {
        int oo = c * 32 + o;
        float f = bf1[oo];
        #pragma unroll 8
        for (int i = 0; i < 32; ++i) f += Wf1_s[oo * 33 + i] * x1s[j * 33 + i];
        fs[j * 65 + oo] = 0.5f * f * (1.f + erff(f * 0.70710678118654752f));
    }
    __syncthreads();

    // FFN2 + residual + LN2
    float f2 = bf2[o];
    #pragma unroll 8
    for (int i = 0; i < 64; ++i) f2 += Wf2_s[o * 65 + i] * fs[j * 65 + i];
    float t2 = x1 + f2;
    float mu2 = t2;
    #pragma unroll
    for (int m = 16; m >= 1; m >>= 1) mu2 += __shfl_xor(mu2, m, 32);
    mu2 *= (1.f / 32.f);
    float dv2 = t2 - mu2;
    float var2 = dv2 * dv2;
    #pragma unroll
    for (int m = 16; m >= 1; m >>= 1) var2 += __shfl_xor(var2, m, 32);
    var2 *= (1.f / 32.f);
    float x2 = dv2 * rsqrtf(var2 + 1e-5f) * g2[o] + be2[o];

    x1s[j * 33 + o] = x2;
    __syncthreads();

    // SCN: 16 outputs, LN over 16, relu -> per-SLOT sout
    if (o < 16) {
        float sc = bscn[o];
        #pragma unroll 8
        for (int i = 0; i < 32; ++i) sc += Ws_s[o * 33 + i] * x1s[j * 33 + i];
        float m16 = sc;
        #pragma unroll
        for (int m = 8; m >= 1; m >>= 1) m16 += __shfl_xor(m16, m, 16);
        m16 *= (1.f / 16.f);
        float d16 = sc - m16;
        float v16 = d16 * d16;
        #pragma unroll
        for (int m = 8; m >= 1; m >>= 1) v16 += __shfl_xor(v16, m, 16);
        v16 *= (1.f / 16.f);
        float sv = d16 * rsqrtf(v16 + 1e-5f) * gscn[o] + bescn[o];
        ws[WS_SOUT + s * 16 + o] = fmaxf(sv, 0.f);
    }
}

// ---------------------------------------------------------------------------
// K4: single wave. Edge-head MLP -> logits; sequential GRU scan over 16 edges.
// ---------------------------------------------------------------------------
__global__ __launch_bounds__(64) void k4_scan(
    const int* __restrict__ src, const int* __restrict__ dst,
    const float* __restrict__ mem,
    const float* __restrict__ Whh, const float* __restrict__ bhh,
    const float* __restrict__ We1, const float* __restrict__ be1e,
    const float* __restrict__ We2, const float* __restrict__ be2e,
    const float* __restrict__ We3, const float* __restrict__ be3,
    float* __restrict__ ws, float* __restrict__ out)
{
    __shared__ float We1_s[32 * 33];
    __shared__ float We2_s[16 * 33];
    __shared__ float cat_s[16 * 33];
    __shared__ float h1_s[16 * 33];
    __shared__ float h2_s[16 * 17];
    __shared__ float gi_s[16 * 97];
    __shared__ __align__(16) float slots[32 * 36];
    __shared__ int nid_s[32], fid_s[32], last_s[32];

    const int l = threadIdx.x;

    for (int idx = l; idx < 1024; idx += 64) { int r = idx >> 5, c = idx & 31; We1_s[r * 33 + c] = We1[idx]; }
    for (int idx = l; idx < 512;  idx += 64) { int r = idx >> 5, c = idx & 31; We2_s[r * 33 + c] = We2[idx]; }
    {
        const float* gi_g = ws + WS_GI;
        for (int idx = l; idx < 1536; idx += 64) { int e = idx / 96, o = idx - e * 96; gi_s[e * 97 + o] = gi_g[idx]; }
    }
    {
        const float* sout = ws + WS_SOUT;
        for (int idx = l; idx < 512; idx += 64) {
            int e = idx >> 5, i = idx & 31;
            cat_s[e * 33 + i] = (i < 16) ? sout[(2 * e) * 16 + i] : sout[(2 * e + 1) * 16 + (i - 16)];
        }
    }
    if (l < 32) nid_s[l] = (l & 1) ? dst[l >> 1] : src[l >> 1];
    __syncthreads();

    if (l < 32) {
        int me = nid_s[l], f = l;
        for (int j2 = 0; j2 < l; ++j2) if (nid_s[j2] == me) { f = j2; break; }
        fid_s[l] = f;
        int isl = 1;
        for (int j2 = l + 1; j2 < 32; ++j2) if (nid_s[j2] == me) { isl = 0; break; }
        last_s[l] = isl;
    }
    __syncthreads();

    // load memory rows into slots (first occurrences only)
    for (int idx = l; idx < 1024; idx += 64) {
        int j2 = idx >> 5, o = idx & 31;
        if (fid_s[j2] == j2) slots[j2 * 36 + o] = mem[nid_s[j2] * 32 + o];
    }

    // ---- edge head ----
    {
        int o = l & 31, eh = l >> 5;
        for (int p = 0; p < 8; ++p) {
            int e = p * 2 + eh;
            float acc = be1e[o];
            #pragma unroll 8
            for (int i = 0; i < 32; ++i) acc += We1_s[o * 33 + i] * cat_s[e * 33 + i];
            h1_s[e * 33 + o] = fmaxf(acc, 0.f);
        }
    }
    __syncthreads();
    {
        int o = l & 15, eh = l >> 4;
        for (int p = 0; p < 4; ++p) {
            int e = p * 4 + eh;
            float acc = be2e[o];
            #pragma unroll 8
            for (int i = 0; i < 32; ++i) acc += We2_s[o * 33 + i] * h1_s[e * 33 + i];
            h2_s[e * 17 + o] = fmaxf(acc, 0.f);
        }
    }
    __syncthreads();
    if (l < 16) {
        float acc = be3[0];
        #pragma unroll
        for (int i = 0; i < 16; ++i) acc += We3[i] * h2_s[l * 17 + i];
        out[l] = acc;
    }
    __syncthreads();

    // ---- GRU scan ----
    const int r2 = (l < 32) ? l + 64 : l - 32;
    const int r3 = l + 32;
    float4 w1[8], w2[8], w3[8];
    #pragma unroll
    for (int c = 0; c < 8; ++c) {
        w1[c] = ((const float4*)Whh)[l * 8 + c];
        w2[c] = ((const float4*)Whh)[r2 * 8 + c];
        w3[c] = ((const float4*)Whh)[r3 * 8 + c];
    }
    const float b1 = bhh[l], b2 = bhh[r2], b3 = bhh[r3];
    const bool lowhalf = (l < 32);
    const int o = l & 31;

    for (int e = 0; e < 16; ++e) {
        const int js = 2 * e, jd = 2 * e + 1;
        const int ss = fid_s[js], sd = fid_s[jd];
        const bool same = (nid_s[js] == nid_s[jd]);
        const int npass = same ? 2 : 1;
        for (int pass = 0; pass < npass; ++pass) {
            const bool do_src = (!same) || (pass == 0);
            const bool do_dst = (!same) || (pass == 1);
            float acc1 = b1, acc2 = b2, acc3 = b3;
            #pragma unroll
            for (int c = 0; c < 8; ++c) {
                const float4 hs4 = *(const float4*)&slots[ss * 36 + 4 * c];
                const float4 hd4 = *(const float4*)&slots[sd * 36 + 4 * c];
                acc1 += dot4_(w1[c], hs4);
                const float4 hm = lowhalf ? hs4 : hd4;
                acc2 += dot4_(w2[c], hm);
                acc3 += dot4_(w3[c], hd4);
            }
            const float shv = __shfl_xor(lowhalf ? acc3 : acc1, 32);
            const float hr = lowhalf ? acc1 : acc2;
            const float hz = shv;
            const float hn = lowhalf ? acc2 : acc3;
            const float ir  = gi_s[e * 97 + o];
            const float iz  = gi_s[e * 97 + 32 + o];
            const float inn = gi_s[e * 97 + 64 + o];
            const float r = sigmoidf_(ir + hr);
            const float z = sigmoidf_(iz + hz);
            const float nn = tanhf_(inn + r * hn);
            const int slot = lowhalf ? ss : sd;
            const float hold = slots[slot * 36 + o];
            const float hnew = (1.f - z) * nn + z * hold;
            const bool wr = lowhalf ? do_src : do_dst;
            if (wr) slots[slot * 36 + o] = hnew;
            __syncthreads();
        }
    }

    // write back last occurrence of each node
    for (int idx = l; idx < 1024; idx += 64) {
        int j2 = idx >> 5, oo = idx & 31;
        if (last_s[j2]) out[16 + nid_s[j2] * 32 + oo] = slots[fid_s[j2] * 36 + oo];
    }
}

// ---------------------------------------------------------------------------
extern "C" void kernel_launch(void* const* d_in, const int* in_sizes, int n_in,
                              void* d_out, int out_size, void* d_ws, size_t ws_size,
                              hipStream_t stream)
{
    (void)in_sizes; (void)n_in; (void)out_size; (void)ws_size;
    const int*   src   = (const int*)d_in[0];
    const int*   dst   = (const int*)d_in[1];
    const float* ef    = (const float*)d_in[2];
    const float* nf    = (const float*)d_in[4];
    const float* mem   = (const float*)d_in[6];
    const float* Wemb  = (const float*)d_in[7];
    const float* bemb  = (const float*)d_in[8];
    const float* Wqkv  = (const float*)d_in[9];
    const float* bqkv  = (const float*)d_in[10];
    const float* Wo    = (const float*)d_in[11];
    const float* bo    = (const float*)d_in[12];
    const float* g1    = (const float*)d_in[13];
    const float* be1   = (const float*)d_in[14];
    const float* g2    = (const float*)d_in[15];
    const float* be2   = (const float*)d_in[16];
    const float* Wf1   = (const float*)d_in[17];
    const float* bf1   = (const float*)d_in[18];
    const float* Wf2   = (const float*)d_in[19];
    const float* bf2   = (const float*)d_in[20];
    const float* Wscn  = (const float*)d_in[21];
    const float* bscn  = (const float*)d_in[22];
    const float* gscn  = (const float*)d_in[23];
    const float* bescn = (const float*)d_in[24];
    const float* We1   = (const float*)d_in[25];
    const float* be1e  = (const float*)d_in[26];
    const float* We2   = (const float*)d_in[27];
    const float* be2e  = (const float*)d_in[28];
    const float* We3   = (const float*)d_in[29];
    const float* be3   = (const float*)d_in[30];
    const float* Wih   = (const float*)d_in[31];
    const float* bih   = (const float*)d_in[32];
    const float* Whh   = (const float*)d_in[33];
    const float* bhh   = (const float*)d_in[34];
    const float* Wm1   = (const float*)d_in[35];
    const float* bm1   = (const float*)d_in[36];
    const float* Wm2   = (const float*)d_in[37];
    const float* bm2   = (const float*)d_in[38];
    float* out = (float*)d_out;
    float* ws  = (float*)d_ws;

    hipLaunchKernelGGL(k1_embed_qkv, dim3(257), dim3(256), 0, stream,
        nf, Wemb, bemb, Wqkv, bqkv, mem, src, dst, ef, Wm1, bm1, Wm2, bm2, Wih, bih, ws);
    hipLaunchKernelGGL(k2_attn, dim3(128), dim3(256), 0, stream, src, dst, mem, ws, out);
    hipLaunchKernelGGL(k3_post, dim3(4), dim3(256), 0, stream,
        src, dst, Wo, bo, g1, be1, Wf1, bf1, Wf2, bf2, g2, be2, Wscn, bscn, gscn, bescn, ws);
    hipLaunchKernelGGL(k4_scan, dim3(1), dim3(64), 0, stream,
        src, dst, mem, Whh, bhh, We1, be1e, We2, be2e, We3, be3, ws, out);
}